// Round 2
// baseline (1505.657 us; speedup 1.0000x reference)
//
#include <hip/hip_runtime.h>
#include <cmath>

#define NLEV 16
#define TPB 256

typedef float v4f __attribute__((ext_vector_type(4)));   // native vector for nontemporal builtin

// Level metadata replicated from the reference's _level_meta() (computed in
// float64 host math; boundary levels 5/10/15 are 1e-5 ABOVE the integer, so
// res=65/257/1025). Compile-time so the unrolled loop folds to immediates.
static constexpr unsigned kRes[NLEV] = {16u,22u,28u,37u,49u,65u,85u,112u,148u,195u,257u,338u,446u,589u,777u,1025u};
static constexpr unsigned kMsz[NLEV] = {4096u,10648u,21952u,50656u,117656u,274632u,
  524288u,524288u,524288u,524288u,524288u,524288u,524288u,524288u,524288u,524288u};
static constexpr unsigned kOff[NLEV] = {0u,4096u,14744u,36696u,87352u,205008u,479640u,1003928u,
  1528216u,2052504u,2576792u,3101080u,3625368u,4149656u,4673944u,5198232u};
static constexpr int kDense[NLEV] = {1,1,1,1,1,1,0,0,0,0,0,0,0,0,0,0};

struct ScaleParams { float s[NLEV]; };

__global__ __launch_bounds__(TPB) void hashenc_kernel(
    const float* __restrict__ pos, const float* __restrict__ table,
    float* __restrict__ out, ScaleParams sp)
{
  __shared__ float lds[TPB * 33];   // 33792 B; reused: pos staging -> out transpose
  const int tid = threadIdx.x;
  const size_t pbase = (size_t)blockIdx.x * TPB;

  // Stage positions: 768 contiguous floats, coalesced.
  {
    const float* src = pos + pbase * 3;
    lds[tid]        = src[tid];
    lds[tid + 256]  = src[tid + 256];
    lds[tid + 512]  = src[tid + 512];
  }
  __syncthreads();
  const float px = lds[tid*3 + 0];
  const float py = lds[tid*3 + 1];
  const float pz = lds[tid*3 + 2];
  __syncthreads();   // lds reused for the output transpose below

  const float2* __restrict__ tab2 = (const float2*)table;
  float acc[2 * NLEV];

#pragma unroll
  for (int L = 0; L < NLEV; ++L) {
    const float scale = sp.s[L];
    const float x = px * scale + 0.5f;
    const float y = py * scale + 0.5f;
    const float z = pz * scale + 0.5f;
    const float xf = floorf(x), yf = floorf(y), zf = floorf(z);
    const float tx = x - xf, ty = y - yf, tz = z - zf;
    const unsigned xi = (unsigned)xf, yi = (unsigned)yf, zi = (unsigned)zf;

    unsigned hx[2], hy[2], hz[2];
    if (kDense[L]) {
      const unsigned r = kRes[L];
      hx[0] = xi;          hx[1] = xi + 1u;
      hy[0] = yi * r;      hy[1] = (yi + 1u) * r;
      hz[0] = zi * r * r;  hz[1] = (zi + 1u) * r * r;
    } else {
      hx[0] = xi;                 hx[1] = xi + 1u;
      hy[0] = yi * 2654435761u;   hy[1] = (yi + 1u) * 2654435761u;
      hz[0] = zi * 805459861u;    hz[1] = (zi + 1u) * 805459861u;
    }
    const float wx[2] = {1.0f - tx, tx};
    const float wy[2] = {1.0f - ty, ty};
    const float wz[2] = {1.0f - tz, tz};

    float a0 = 0.0f, a1 = 0.0f;
#pragma unroll
    for (int c = 0; c < 8; ++c) {
      unsigned idx;
      if (kDense[L]) {
        // h < 2*msize provably (h <= res*(1+res+res^2) < 2*res^3 <= 2*msize)
        unsigned h = hx[c & 1] + hy[(c >> 1) & 1] + hz[(c >> 2) & 1];
        idx = (h >= kMsz[L]) ? (h - kMsz[L]) : h;
      } else {
        idx = (hx[c & 1] ^ hy[(c >> 1) & 1] ^ hz[(c >> 2) & 1]) & (kMsz[L] - 1u);
      }
      const float2 f = tab2[kOff[L] + idx];
      const float w = wx[c & 1] * wy[(c >> 1) & 1] * wz[(c >> 2) & 1];
      a0 = fmaf(w, f.x, a0);
      a1 = fmaf(w, f.y, a1);
    }
    acc[2 * L]     = a0;
    acc[2 * L + 1] = a1;
  }

  // LDS transpose (pad 33 -> conflict-free) for fully coalesced float4 stores.
#pragma unroll
  for (int c = 0; c < 32; ++c) lds[tid * 33 + c] = acc[c];
  __syncthreads();

  v4f* out4 = (v4f*)out + (size_t)blockIdx.x * (TPB * 32 / 4);
#pragma unroll
  for (int k = 0; k < 8; ++k) {
    const int q  = tid + k * TPB;   // float4 index in [0, 2048)
    const int p  = q >> 3;          // local point
    const int c4 = (q & 7) * 4;     // channel start
    v4f v;
    v.x = lds[p * 33 + c4 + 0];
    v.y = lds[p * 33 + c4 + 1];
    v.z = lds[p * 33 + c4 + 2];
    v.w = lds[p * 33 + c4 + 3];
    __builtin_nontemporal_store(v, out4 + q);  // keep 268MB store stream out of L2
  }
}

extern "C" void kernel_launch(void* const* d_in, const int* in_sizes, int n_in,
                              void* d_out, int out_size, void* d_ws, size_t ws_size,
                              hipStream_t stream) {
  const float* pos   = (const float*)d_in[0];
  const float* table = (const float*)d_in[1];
  float* out = (float*)d_out;

  // Float32 scale bits must match numpy: compute in double on host.
  ScaleParams sp;
  for (int i = 0; i < NLEV; ++i)
    sp.s[i] = (float)(16.0 * exp((double)i * log(1.3195079565048218)) - 1.0);

  const int npts = in_sizes[0] / 3;   // 2097152
  hashenc_kernel<<<npts / TPB, TPB, 0, stream>>>(pos, table, out, sp);
}

// Round 3
// 1066.757 us; speedup vs baseline: 1.4114x; 1.4114x over previous
//
#include <hip/hip_runtime.h>
#include <cmath>

#define NLEV 16
#define TPB 256

typedef float v4f __attribute__((ext_vector_type(4)));
typedef float v2f __attribute__((ext_vector_type(2)));

// Level metadata replicated from the reference's _level_meta() (float64 host
// math; boundary levels 5/10/15 land 1e-5 ABOVE the integer -> res=65/257/1025).
static constexpr unsigned kRes[NLEV] = {16u,22u,28u,37u,49u,65u,85u,112u,148u,195u,257u,338u,446u,589u,777u,1025u};
static constexpr unsigned kMsz[NLEV] = {4096u,10648u,21952u,50656u,117656u,274632u,
  524288u,524288u,524288u,524288u,524288u,524288u,524288u,524288u,524288u,524288u};
static constexpr unsigned kOff[NLEV] = {0u,4096u,14744u,36696u,87352u,205008u,479640u,1003928u,
  1528216u,2052504u,2576792u,3101080u,3625368u,4149656u,4673944u,5198232u};
static constexpr int kDense[NLEV] = {1,1,1,1,1,1,0,0,0,0,0,0,0,0,0,0};

struct ScaleParams { float s[NLEV]; };

// ---------------------------------------------------------------------------
// Staged path: one kernel per hashed level (4MB table -> L2-resident per XCD),
// dense levels 0-5 together (3.84MB total), level-major ws, final transpose.
// ---------------------------------------------------------------------------

__device__ __forceinline__ void load_pos(const float* __restrict__ pos, float* sp,
                                         int tid, size_t pbase,
                                         float& px, float& py, float& pz) {
  const float* src = pos + pbase * 3;
  sp[tid]       = __builtin_nontemporal_load(src + tid);
  sp[tid + 256] = __builtin_nontemporal_load(src + tid + 256);
  sp[tid + 512] = __builtin_nontemporal_load(src + tid + 512);
  __syncthreads();
  px = sp[tid*3 + 0]; py = sp[tid*3 + 1]; pz = sp[tid*3 + 2];
}

template<int L>
__global__ __launch_bounds__(TPB, 8) void hash_level(
    const float* __restrict__ pos, const float* __restrict__ table,
    float* __restrict__ ws, float scale, int npts)
{
  __shared__ float sp[TPB * 3];
  const int tid = threadIdx.x;
  const size_t pbase = (size_t)blockIdx.x * TPB;
  float px, py, pz;
  load_pos(pos, sp, tid, pbase, px, py, pz);

  const float x = px * scale + 0.5f;
  const float y = py * scale + 0.5f;
  const float z = pz * scale + 0.5f;
  const float xf = floorf(x), yf = floorf(y), zf = floorf(z);
  const float tx = x - xf, ty = y - yf, tz = z - zf;
  const unsigned xi = (unsigned)xf, yi = (unsigned)yf, zi = (unsigned)zf;

  const unsigned hx[2] = {xi, xi + 1u};
  const unsigned hy[2] = {yi * 2654435761u, (yi + 1u) * 2654435761u};
  const unsigned hz[2] = {zi * 805459861u,  (zi + 1u) * 805459861u};
  const float wx[2] = {1.0f - tx, tx};
  const float wy[2] = {1.0f - ty, ty};
  const float wz[2] = {1.0f - tz, tz};

  const float2* __restrict__ tab2 = (const float2*)table;
  float a0 = 0.0f, a1 = 0.0f;
#pragma unroll
  for (int c = 0; c < 8; ++c) {
    const unsigned idx = (hx[c & 1] ^ hy[(c >> 1) & 1] ^ hz[(c >> 2) & 1]) & (kMsz[L] - 1u);
    const float2 f = tab2[kOff[L] + idx];
    const float w = wx[c & 1] * wy[(c >> 1) & 1] * wz[(c >> 2) & 1];
    a0 = fmaf(w, f.x, a0);
    a1 = fmaf(w, f.y, a1);
  }
  v2f r; r.x = a0; r.y = a1;
  __builtin_nontemporal_store(r, (v2f*)ws + (size_t)L * npts + pbase + tid);
}

__global__ __launch_bounds__(TPB, 4) void dense_levels(
    const float* __restrict__ pos, const float* __restrict__ table,
    float* __restrict__ ws, ScaleParams spar, int npts)
{
  __shared__ float sp[TPB * 3];
  const int tid = threadIdx.x;
  const size_t pbase = (size_t)blockIdx.x * TPB;
  float px, py, pz;
  load_pos(pos, sp, tid, pbase, px, py, pz);

  const float2* __restrict__ tab2 = (const float2*)table;
#pragma unroll
  for (int L = 0; L < 6; ++L) {
    const float scale = spar.s[L];
    const float x = px * scale + 0.5f;
    const float y = py * scale + 0.5f;
    const float z = pz * scale + 0.5f;
    const float xf = floorf(x), yf = floorf(y), zf = floorf(z);
    const float tx = x - xf, ty = y - yf, tz = z - zf;
    const unsigned xi = (unsigned)xf, yi = (unsigned)yf, zi = (unsigned)zf;

    const unsigned r = kRes[L];
    const unsigned hx[2] = {xi, xi + 1u};
    const unsigned hy[2] = {yi * r, (yi + 1u) * r};
    const unsigned hz[2] = {zi * r * r, (zi + 1u) * r * r};
    const float wx[2] = {1.0f - tx, tx};
    const float wy[2] = {1.0f - ty, ty};
    const float wz[2] = {1.0f - tz, tz};

    float a0 = 0.0f, a1 = 0.0f;
#pragma unroll
    for (int c = 0; c < 8; ++c) {
      // h < 2*msize provably (h <= r*(1+r+r^2) < 2*r^3 <= 2*msize)
      const unsigned h = hx[c & 1] + hy[(c >> 1) & 1] + hz[(c >> 2) & 1];
      const unsigned idx = (h >= kMsz[L]) ? (h - kMsz[L]) : h;
      const float2 f = tab2[kOff[L] + idx];
      const float w = wx[c & 1] * wy[(c >> 1) & 1] * wz[(c >> 2) & 1];
      a0 = fmaf(w, f.x, a0);
      a1 = fmaf(w, f.y, a1);
    }
    v2f rr; rr.x = a0; rr.y = a1;
    __builtin_nontemporal_store(rr, (v2f*)ws + (size_t)L * npts + pbase + tid);
  }
}

__global__ __launch_bounds__(TPB, 4) void transpose_out(
    const float* __restrict__ ws, float* __restrict__ out, int npts)
{
  __shared__ float lds[TPB * 33];
  const int tid = threadIdx.x;
  const size_t pbase = (size_t)blockIdx.x * TPB;
#pragma unroll
  for (int L = 0; L < NLEV; ++L) {
    const v2f w = __builtin_nontemporal_load((const v2f*)ws + (size_t)L * npts + pbase + tid);
    lds[tid * 33 + 2 * L]     = w.x;
    lds[tid * 33 + 2 * L + 1] = w.y;
  }
  __syncthreads();
  v4f* out4 = (v4f*)out + (size_t)blockIdx.x * (TPB * 32 / 4);
#pragma unroll
  for (int k = 0; k < 8; ++k) {
    const int q  = tid + k * TPB;
    const int p  = q >> 3;
    const int c4 = (q & 7) * 4;
    v4f v;
    v.x = lds[p * 33 + c4 + 0];
    v.y = lds[p * 33 + c4 + 1];
    v.z = lds[p * 33 + c4 + 2];
    v.w = lds[p * 33 + c4 + 3];
    __builtin_nontemporal_store(v, out4 + q);
  }
}

// ---------------------------------------------------------------------------
// Fallback monolithic kernel (R2: passed, 1300us) if ws is too small.
// ---------------------------------------------------------------------------
__global__ __launch_bounds__(TPB) void hashenc_kernel(
    const float* __restrict__ pos, const float* __restrict__ table,
    float* __restrict__ out, ScaleParams spar)
{
  __shared__ float lds[TPB * 33];
  const int tid = threadIdx.x;
  const size_t pbase = (size_t)blockIdx.x * TPB;
  {
    const float* src = pos + pbase * 3;
    lds[tid]        = src[tid];
    lds[tid + 256]  = src[tid + 256];
    lds[tid + 512]  = src[tid + 512];
  }
  __syncthreads();
  const float px = lds[tid*3 + 0];
  const float py = lds[tid*3 + 1];
  const float pz = lds[tid*3 + 2];
  __syncthreads();

  const float2* __restrict__ tab2 = (const float2*)table;
  float acc[2 * NLEV];

#pragma unroll
  for (int L = 0; L < NLEV; ++L) {
    const float scale = spar.s[L];
    const float x = px * scale + 0.5f;
    const float y = py * scale + 0.5f;
    const float z = pz * scale + 0.5f;
    const float xf = floorf(x), yf = floorf(y), zf = floorf(z);
    const float tx = x - xf, ty = y - yf, tz = z - zf;
    const unsigned xi = (unsigned)xf, yi = (unsigned)yf, zi = (unsigned)zf;

    unsigned hx[2], hy[2], hz[2];
    if (kDense[L]) {
      const unsigned r = kRes[L];
      hx[0] = xi;          hx[1] = xi + 1u;
      hy[0] = yi * r;      hy[1] = (yi + 1u) * r;
      hz[0] = zi * r * r;  hz[1] = (zi + 1u) * r * r;
    } else {
      hx[0] = xi;                 hx[1] = xi + 1u;
      hy[0] = yi * 2654435761u;   hy[1] = (yi + 1u) * 2654435761u;
      hz[0] = zi * 805459861u;    hz[1] = (zi + 1u) * 805459861u;
    }
    const float wx[2] = {1.0f - tx, tx};
    const float wy[2] = {1.0f - ty, ty};
    const float wz[2] = {1.0f - tz, tz};

    float a0 = 0.0f, a1 = 0.0f;
#pragma unroll
    for (int c = 0; c < 8; ++c) {
      unsigned idx;
      if (kDense[L]) {
        unsigned h = hx[c & 1] + hy[(c >> 1) & 1] + hz[(c >> 2) & 1];
        idx = (h >= kMsz[L]) ? (h - kMsz[L]) : h;
      } else {
        idx = (hx[c & 1] ^ hy[(c >> 1) & 1] ^ hz[(c >> 2) & 1]) & (kMsz[L] - 1u);
      }
      const float2 f = tab2[kOff[L] + idx];
      const float w = wx[c & 1] * wy[(c >> 1) & 1] * wz[(c >> 2) & 1];
      a0 = fmaf(w, f.x, a0);
      a1 = fmaf(w, f.y, a1);
    }
    acc[2 * L]     = a0;
    acc[2 * L + 1] = a1;
  }

#pragma unroll
  for (int c = 0; c < 32; ++c) lds[tid * 33 + c] = acc[c];
  __syncthreads();

  v4f* out4 = (v4f*)out + (size_t)blockIdx.x * (TPB * 32 / 4);
#pragma unroll
  for (int k = 0; k < 8; ++k) {
    const int q  = tid + k * TPB;
    const int p  = q >> 3;
    const int c4 = (q & 7) * 4;
    v4f v;
    v.x = lds[p * 33 + c4 + 0];
    v.y = lds[p * 33 + c4 + 1];
    v.z = lds[p * 33 + c4 + 2];
    v.w = lds[p * 33 + c4 + 3];
    __builtin_nontemporal_store(v, out4 + q);
  }
}

extern "C" void kernel_launch(void* const* d_in, const int* in_sizes, int n_in,
                              void* d_out, int out_size, void* d_ws, size_t ws_size,
                              hipStream_t stream) {
  const float* pos   = (const float*)d_in[0];
  const float* table = (const float*)d_in[1];
  float* out = (float*)d_out;

  ScaleParams sp;
  for (int i = 0; i < NLEV; ++i)
    sp.s[i] = (float)(16.0 * exp((double)i * log(1.3195079565048218)) - 1.0);

  const int npts = in_sizes[0] / 3;   // 2097152
  const int nblk = npts / TPB;
  const size_t need = (size_t)npts * 32 * sizeof(float);

  if (ws_size >= need) {
    float* wsf = (float*)d_ws;
    dense_levels<<<nblk, TPB, 0, stream>>>(pos, table, wsf, sp, npts);
    hash_level< 6><<<nblk, TPB, 0, stream>>>(pos, table, wsf, sp.s[ 6], npts);
    hash_level< 7><<<nblk, TPB, 0, stream>>>(pos, table, wsf, sp.s[ 7], npts);
    hash_level< 8><<<nblk, TPB, 0, stream>>>(pos, table, wsf, sp.s[ 8], npts);
    hash_level< 9><<<nblk, TPB, 0, stream>>>(pos, table, wsf, sp.s[ 9], npts);
    hash_level<10><<<nblk, TPB, 0, stream>>>(pos, table, wsf, sp.s[10], npts);
    hash_level<11><<<nblk, TPB, 0, stream>>>(pos, table, wsf, sp.s[11], npts);
    hash_level<12><<<nblk, TPB, 0, stream>>>(pos, table, wsf, sp.s[12], npts);
    hash_level<13><<<nblk, TPB, 0, stream>>>(pos, table, wsf, sp.s[13], npts);
    hash_level<14><<<nblk, TPB, 0, stream>>>(pos, table, wsf, sp.s[14], npts);
    hash_level<15><<<nblk, TPB, 0, stream>>>(pos, table, wsf, sp.s[15], npts);
    transpose_out<<<nblk, TPB, 0, stream>>>(wsf, out, npts);
  } else {
    hashenc_kernel<<<nblk, TPB, 0, stream>>>(pos, table, out, sp);
  }
}